// Round 1
// baseline (175.647 us; speedup 1.0000x reference)
//
#include <hip/hip_runtime.h>

typedef _Float16 f16;
typedef _Float16 f16x2 __attribute__((ext_vector_type(2)));
typedef _Float16 f16x4 __attribute__((ext_vector_type(4)));
typedef _Float16 f16x8 __attribute__((ext_vector_type(8)));
typedef float    f32x4 __attribute__((ext_vector_type(4)));
typedef unsigned int u32;
typedef u32      u32x2 __attribute__((ext_vector_type(2)));
typedef u32      u32x4 __attribute__((ext_vector_type(4)));

#define MFMA32(a, b, c) __builtin_amdgcn_mfma_f32_16x16x32_f16((a), (b), (c), 0, 0, 0)
// NOTE: legacy K=16 intrinsic has NO underscore before f16 on gfx950
#define MFMA16(a, b, c) __builtin_amdgcn_mfma_f32_16x16x16f16((a), (b), (c), 0, 0, 0)

__device__ __forceinline__ float leaky(float x) {
    return fmaf(0.4f, __builtin_fabsf(x), 0.6f * x);
}
__device__ __forceinline__ u32 pkrtz(float a, float b) {
    return __builtin_bit_cast(u32, __builtin_amdgcn_cvt_pkrtz(a, b));
}
// pack 2 f32 -> f16 pair, then leaky in PACKED f16 math (pk_max/pk_min/
// pk_fma = 3 ops/2elem + pkrtz, vs 5 in f32). max/min form keeps positive
// values exact; only the negative branch sees f16-0.2 (2.4e-4 rel).
__device__ __forceinline__ u32 lk_pk2(float a, float b) {
    f16x2 v = __builtin_bit_cast(f16x2, __builtin_amdgcn_cvt_pkrtz(a, b));
    f16x2 z2 = {(f16)0.0f, (f16)0.0f};
    f16x2 mx = __builtin_elementwise_max(v, z2);
    f16x2 mn = __builtin_elementwise_min(v, z2);
    f16x2 r = mn * (f16x2){(f16)0.2f, (f16)0.2f} + mx;
    return __builtin_bit_cast(u32, r);
}
__device__ __forceinline__ f16x4 lk_pk4(const f32x4 z) {
    return __builtin_bit_cast(f16x4, (u32x2){ lk_pk2(z[0], z[1]), lk_pk2(z[2], z[3]) });
}
__device__ __forceinline__ f16x4 pk4(const f32x4 z) {
    return __builtin_bit_cast(f16x4, (u32x2){ pkrtz(z[0], z[1]), pkrtz(z[2], z[3]) });
}
__device__ __forceinline__ void st_lk4(void* p, const f32x4 z) {
    *(u32x2*)p = (u32x2){ lk_pk2(z[0], z[1]), lk_pk2(z[2], z[3]) };
}

// ---------------------------------------------------------------------------
// Prepack: f16 MFMA fragments in d_ws (unchanged).
// ---------------------------------------------------------------------------
__global__ void disc_prepack(const float* __restrict__ Wp1, const float* __restrict__ Wp2,
                             const float* __restrict__ Wn1, const float* __restrict__ Wn2,
                             const float* __restrict__ Wl1, const float* __restrict__ Wl2,
                             f16* __restrict__ ws)
{
    int idx = blockIdx.x * 256 + threadIdx.x;
    if (idx >= 84 * 512 + 24 * 256) return;
    float v = 0.0f;
    if (idx < 84 * 512) {
        int f = idx >> 9, r = idx & 511;
        int lane = r >> 3, e = r & 7;
        int m15 = lane & 15, h = lane >> 4;
        if (f < 64) {
            int mt4 = f >> 4, ks4 = f & 15;
            int k = ks4 * 32 + h * 8 + e;
            v = Wl1[k * 64 + mt4 * 16 + m15];
        } else if (f < 72) {
            int q = f - 64, c = q >> 2, mt = q & 3;
            const float* W1 = c ? Wn1 : Wp1;
            v = (lane < 16) ? W1[e * 64 + mt * 16 + m15] : 0.0f;
        } else if (f < 80) {
            int q = f - 72, c = q >> 2, nt2 = (q >> 1) & 1, ks2 = q & 1;
            const float* W2 = c ? Wn2 : Wp2;
            int k = ks2 * 32 + h * 8 + e;
            v = W2[k * 32 + nt2 * 16 + m15];
        } else {
            int q = f - 80, ms5 = q >> 1, ks5 = q & 1;
            int k = ks5 * 32 + h * 8 + e;
            v = Wl2[k * 32 + ms5 * 16 + m15];
        }
    } else {
        int r2 = idx - 84 * 512;
        int f2 = r2 >> 8, rr = r2 & 255;
        int lane = rr >> 2, e = rr & 3;
        int m15 = lane & 15, h = lane >> 4;
        if (f2 < 16) {
            int c = f2 >> 3, kb = (f2 >> 1) & 3, nt = f2 & 1;
            const float* W2 = c ? Wn2 : Wp2;
            v = W2[(kb * 16 + h * 4 + e) * 32 + nt * 16 + m15];
        } else {
            int q = f2 - 16, kb = q >> 1, nt = q & 1;
            v = Wl2[(kb * 16 + h * 4 + e) * 32 + nt * 16 + m15];
        }
    }
    ws[idx] = (f16)v;
}

// ---------------------------------------------------------------------------
// R14: 4-wave blocks for 2x occupancy.
//   wave = (c = wid>>1, half = wid&1). Each wave runs Phase A/B for its
//   channel's batch-half (t in [4*half, 4*half+4), 2 interleaved streams),
//   then Phase C over its K-quarter (k8 in [4*half, 4*half+4)) with the
//   full N=16 batch tile. Total MFMA per block identical to R13; per-wave
//   serial chain halved; LDS/block unchanged at 20480 B ->
//   8 blocks x 256 thr = 2048 thr = 32 waves/CU (100% theoretical occ).
//   Also: 1.0f/s divide -> v_rcp_f32 (saves ~9 VALU per Phase-A row).
// LDS layout: [0,4096) Albuf per wave (1 KB each, private);
//             [4096,12288) xbuf ch0; [12288,20480) xbuf ch1;
//             xchg = [0,12288) reused post-C for 3x4KB partials.
// ---------------------------------------------------------------------------
__global__ __launch_bounds__(256, 8) void disc_main(
    const float* __restrict__ adj,
    const float* __restrict__ bp1, const float* __restrict__ bp2,
    const float* __restrict__ bn1, const float* __restrict__ bn2,
    const float* __restrict__ bl1, const float* __restrict__ bl2,
    const float* __restrict__ bl3, const float* __restrict__ Wl3,
    const f16* __restrict__ ws, float* __restrict__ out)
{
    extern __shared__ char smem[];
    const int tid  = threadIdx.x;
    const int lane = tid & 63;
    const int wid  = tid >> 6;
    const int c    = wid >> 1;      // channel this wave owns
    const int half = wid & 1;       // batch-half (A/B) and K-quarter (C)
    const int h    = lane >> 4;
    const int m15  = lane & 15;
    const int i7   = lane & 7;
    const int r8   = m15 >> 3;

    const f16x8* wsf = (const f16x8*)ws;
    const f16x4* wsq = (const f16x4*)(ws + 84 * 512);   // 16x16x16 B-frags

    // ---- this wave's channel weights/biases (runtime c in addresses only) --
    const f16x8* w1p = wsf + (64 + c * 4) * 64 + lane;
    f16x8 w1t0 = w1p[0], w1t1 = w1p[64], w1t2 = w1p[128], w1t3 = w1p[192];
    const f16x4* w2p = wsq + (c * 8) * 64 + lane;
    f16x4 w2k00 = w2p[0],   w2k01 = w2p[64];    // kb=0, nt=0/1
    f16x4 w2k10 = w2p[128], w2k11 = w2p[192];   // kb=1
    f16x4 w2k20 = w2p[256], w2k21 = w2p[320];   // kb=2
    f16x4 w2k30 = w2p[384], w2k31 = w2p[448];   // kb=3
    const f32x4* b1p = (const f32x4*)(c ? bn1 : bp1);
    f32x4 b10 = b1p[h], b11 = b1p[4 + h], b12 = b1p[8 + h], b13 = b1p[12 + h];
    const f32x4* b2p = (const f32x4*)(c ? bn2 : bp2);
    f32x4 b20 = b2p[h], b21 = b2p[4 + h];

    char* Albuf = smem + wid * 1024;            // wave-private, 64 rows x 16 B
    char* xbuf  = smem + 4096 + c * 8192;       // per-channel 8 KB (8 x 1KB frags)
    char* xchg  = smem;                          // 12 KB exchange (dead post-C)

    const long b0 = (long)blockIdx.x * 16;
    const int rxor = ((m15 >> 1) & 3) << 4;
    const bool bsel = ((h >> 1) == r8);    // s3 B-frag block-diag gate
    const int  hlow = h & 1;               // s3 B-frag row-half select
    f32x4 zero4 = {0.0f, 0.0f, 0.0f, 0.0f};
    f16x4 zf4 = {};

    // ---- Phase A: load this wave's 64 adj rows, normalize, stage ----
    {
        const int rid = half * 64 + lane;      // global rid = batch*8 + noderow
        const f32x4* rp = (const f32x4*)(adj + (b0 + (rid >> 3)) * 128 + c * 64 + (rid & 7) * 8);
        f32x4 a0 = rp[0];
        f32x4 a1 = rp[1];
        float s = ((a0[0] + a0[1]) + (a0[2] + a0[3])) + ((a1[0] + a1[1]) + (a1[2] + a1[3]));
        float rv = (s > 0.0f) ? __builtin_amdgcn_rcpf(s) : 0.0f;
        f16x8 row;
        row[0] = (f16)(a0[0] * rv); row[1] = (f16)(a0[1] * rv);
        row[2] = (f16)(a0[2] * rv); row[3] = (f16)(a0[3] * rv);
        row[4] = (f16)(a1[0] * rv); row[5] = (f16)(a1[1] * rv);
        row[6] = (f16)(a1[2] * rv); row[7] = (f16)(a1[3] * rv);
        *(f16x8*)(Albuf + lane * 16) = row;    // local row = lane
    }

    // ---- Phase B: fused GCN, TWO independent t-streams (tla=tp, tlb=tp+2) --
    #pragma unroll 1
    for (int tp = 0; tp < 2; ++tp) {
        const int tla = tp, tlb = tp + 2;            // local t (Albuf rows)
        const int ta = half * 4 + tla;               // global t (xbuf rows)
        const int tb = half * 4 + tlb;
        f16x8 arow_a = *(const f16x8*)(Albuf + (((2 * tla + r8) * 8 + i7) << 4));
        f16x8 arow_b = *(const f16x8*)(Albuf + (((2 * tlb + r8) * 8 + i7) << 4));

        // s1 both: z^T = W1^T @ A^T + b1 (16x16x32, K=8 pad)
        f32x4 z0a = MFMA32(w1t0, arow_a, b10);
        f32x4 z1a = MFMA32(w1t1, arow_a, b11);
        f32x4 z2a = MFMA32(w1t2, arow_a, b12);
        f32x4 z3a = MFMA32(w1t3, arow_a, b13);
        f32x4 z0b = MFMA32(w1t0, arow_b, b10);
        f32x4 z1b = MFMA32(w1t1, arow_b, b11);
        f32x4 z2b = MFMA32(w1t2, arow_b, b12);
        f32x4 z3b = MFMA32(w1t3, arow_b, b13);

        // s1 -> s2: register pack+leaky (packed f16 math)
        f16x4 xa0 = lk_pk4(z0a), xa1 = lk_pk4(z1a), xa2 = lk_pk4(z2a), xa3 = lk_pk4(z3a);
        f16x4 xb0 = lk_pk4(z0b), xb1 = lk_pk4(z1b), xb2 = lk_pk4(z2b), xb3 = lk_pk4(z3b);

        // s2 both: y_nt = sum_kb x1 @ W2 (4-chain of 16x16x16, 4 indep chains)
        f32x4 y0a = MFMA16(xa0, w2k00, zero4);
        f32x4 y1a = MFMA16(xa0, w2k01, zero4);
        f32x4 y0b = MFMA16(xb0, w2k00, zero4);
        f32x4 y1b = MFMA16(xb0, w2k01, zero4);
        y0a = MFMA16(xa1, w2k10, y0a);
        y1a = MFMA16(xa1, w2k11, y1a);
        y0b = MFMA16(xb1, w2k10, y0b);
        y1b = MFMA16(xb1, w2k11, y1b);
        y0a = MFMA16(xa2, w2k20, y0a);
        y1a = MFMA16(xa2, w2k21, y1a);
        y0b = MFMA16(xb2, w2k20, y0b);
        y1b = MFMA16(xb2, w2k21, y1b);
        y0a = MFMA16(xa3, w2k30, y0a);
        y1a = MFMA16(xa3, w2k31, y1a);
        y0b = MFMA16(xb3, w2k30, y0b);
        y1b = MFMA16(xb3, w2k31, y1b);

        // s2 -> s3: register pkrtz; B-frag from arow select (block-diag)
        f16x4 pa0 = pk4(y0a), pa1 = pk4(y1a);
        f16x4 pb0 = pk4(y0b), pb1 = pk4(y1b);
        u32x4 ara = __builtin_bit_cast(u32x4, arow_a);
        u32x4 arb = __builtin_bit_cast(u32x4, arow_b);
        f16x4 halfa = __builtin_bit_cast(f16x4,
            hlow ? (u32x2){ara[2], ara[3]} : (u32x2){ara[0], ara[1]});
        f16x4 halfb = __builtin_bit_cast(f16x4,
            hlow ? (u32x2){arb[2], arb[3]} : (u32x2){arb[0], arb[1]});
        f16x4 bfra = bsel ? halfa : zf4;
        f16x4 bfrb = bsel ? halfb : zf4;

        // s3 both: x2^T = y^T @ BD_A^T + b2 (16x16x16, K=16 exact)
        f32x4 x2aa = MFMA16(pa0, bfra, b20);
        f32x4 x2ba = MFMA16(pa1, bfra, b21);
        f32x4 x2ab = MFMA16(pb0, bfrb, b20);
        f32x4 x2bb = MFMA16(pb1, bfrb, b21);

        // leaky+pack + swizzled xbuf writes; slot = i7, n = 2t+r8 (global t)
        const int lga = h >> 1;
        const int lgb = (lga + 2) & 3;
        char* fb = xbuf + (i7 << 10);
        {
            int wx = ((ta & 3) ^ i7) << 4;
            int basew = ((2 * ta + r8) << 6) + ((h & 1) << 3);
            st_lk4(fb + ((basew + lga * 16) ^ wx), x2aa);
            st_lk4(fb + ((basew + lgb * 16) ^ wx), x2ba);
        }
        {
            int wx = ((tb & 3) ^ i7) << 4;
            int basew = ((2 * tb + r8) << 6) + ((h & 1) << 3);
            st_lk4(fb + ((basew + lga * 16) ^ wx), x2ab);
            st_lk4(fb + ((basew + lgb * 16) ^ wx), x2bb);
        }
    }

    // both halves of this channel's xbuf must be complete before Phase C
    __syncthreads();

    // ---- Phase C: h1 partial += Wl1^T[K-quarter] @ x^T (K=128, 16x16x32) ---
    f32x4 a40 = zero4, a41 = zero4, a42 = zero4, a43 = zero4;
    if (wid == 0) {
        a40 = ((const f32x4*)bl1)[h];
        a41 = ((const f32x4*)bl1)[4 + h];
        a42 = ((const f32x4*)bl1)[8 + h];
        a43 = ((const f32x4*)bl1)[12 + h];
    }
    __builtin_amdgcn_s_setprio(1);
    const int kbase = half * 4;
    #pragma unroll
    for (int kq = 0; kq < 4; ++kq) {
        const int k8 = kbase + kq;
        int xr = rxor ^ (k8 << 4);
        f16x8 xf = *(const f16x8*)(xbuf + (k8 << 10) + ((m15 * 64 + h * 16) ^ xr));
        const f16x8* wl = wsf + (c * 8 + k8) * 64 + lane;
        a40 = MFMA32(wl[0],    xf, a40);
        a41 = MFMA32(wl[1024], xf, a41);
        a42 = MFMA32(wl[2048], xf, a42);
        a43 = MFMA32(wl[3072], xf, a43);
    }
    __builtin_amdgcn_s_setprio(0);

    // ---- cross-wave partial exchange (waves 1..3 -> wave0) ----
    __syncthreads();                 // all C reads done; xchg may overwrite
    if (wid) {
        char* dst = xchg + (wid - 1) * 4096 + lane * 16;
        *(f32x4*)(dst +    0) = a40;
        *(f32x4*)(dst + 1024) = a41;
        *(f32x4*)(dst + 2048) = a42;
        *(f32x4*)(dst + 3072) = a43;
    }
    __syncthreads();
    if (wid == 0) {
        #pragma unroll
        for (int p = 0; p < 3; ++p) {
            const f32x4* xp = (const f32x4*)(xchg + p * 4096 + lane * 16);
            a40 += xp[0];
            a41 += xp[64];
            a42 += xp[128];
            a43 += xp[192];
        }

        // ---- Phase D: register pack+leaky of h1 (A-frags for E) ----
        f16x4 pd0 = lk_pk4(a40), pd1 = lk_pk4(a41);
        f16x4 pd2 = lk_pk4(a42), pd3 = lk_pk4(a43);

        // ---- Phase E: h2 = h1 @ Wl2 + bl2 (4-chain 16x16x16 per nt) ----
        const f16x4* wl2p = wsq + 16 * 64 + lane;
        f16x4 l200 = wl2p[0],   l201 = wl2p[64];    // kb=0 nt=0/1
        f16x4 l210 = wl2p[128], l211 = wl2p[192];
        f16x4 l220 = wl2p[256], l221 = wl2p[320];
        f16x4 l230 = wl2p[384], l231 = wl2p[448];
        float c0 = bl2[m15], c1 = bl2[m15 + 16];
        f32x4 a50 = {c0, c0, c0, c0};
        f32x4 a51 = {c1, c1, c1, c1};
        a50 = MFMA16(pd0, l200, a50);
        a51 = MFMA16(pd0, l201, a51);
        a50 = MFMA16(pd1, l210, a50);
        a51 = MFMA16(pd1, l211, a51);
        a50 = MFMA16(pd2, l220, a50);
        a51 = MFMA16(pd2, l221, a51);
        a50 = MFMA16(pd3, l230, a50);
        a51 = MFMA16(pd3, l231, a51);

        // ---- Phase F: out[b=4h+r] = sum_l2 leaky(h2) Wl3 + bl3 ----
        float w30 = Wl3[m15], w31 = Wl3[m15 + 16];
        const float bl3s = bl3[0];
        #pragma unroll
        for (int r = 0; r < 4; ++r) {
            float acc = leaky(a50[r]) * w30 + leaky(a51[r]) * w31;
            acc += __shfl_xor(acc, 1);
            acc += __shfl_xor(acc, 2);
            acc += __shfl_xor(acc, 4);
            acc += __shfl_xor(acc, 8);
            if (m15 == 0) out[b0 + h * 4 + r] = acc + bl3s;
        }
    }
}

extern "C" void kernel_launch(void* const* d_in, const int* in_sizes, int n_in,
                              void* d_out, int out_size, void* d_ws, size_t ws_size,
                              hipStream_t stream)
{
    const float* adj  = (const float*)d_in[0];
    const float* Wp1  = (const float*)d_in[1];
    const float* bp1  = (const float*)d_in[2];
    const float* Wp2  = (const float*)d_in[3];
    const float* bp2  = (const float*)d_in[4];
    const float* Wn1  = (const float*)d_in[5];
    const float* bn1  = (const float*)d_in[6];
    const float* Wn2  = (const float*)d_in[7];
    const float* bn2  = (const float*)d_in[8];
    const float* Wl1  = (const float*)d_in[9];
    const float* bl1  = (const float*)d_in[10];
    const float* Wl2  = (const float*)d_in[11];
    const float* bl2  = (const float*)d_in[12];
    const float* Wl3  = (const float*)d_in[13];
    const float* bl3  = (const float*)d_in[14];
    f16* ws = (f16*)d_ws;
    float* out = (float*)d_out;

    // 84*512 + 24*256 = 49152 f16; 192 blocks x 256 threads
    hipLaunchKernelGGL(disc_prepack, dim3(192), dim3(256), 0, stream,
                       Wp1, Wp2, Wn1, Wn2, Wl1, Wl2, ws);

    const int ldsBytes = 20480;  // Albuf 4x1K + xbuf 2x8K; xchg overlaps
    hipFuncSetAttribute(reinterpret_cast<const void*>(disc_main),
                        hipFuncAttributeMaxDynamicSharedMemorySize, ldsBytes);
    hipLaunchKernelGGL(disc_main, dim3(8192), dim3(256), ldsBytes, stream,
                       adj, bp1, bp2, bn1, bn2, bl1, bl2, bl3, Wl3, ws, out);
}

// Round 2
// 60.788 us; speedup vs baseline: 2.8895x; 2.8895x over previous
//
#include <hip/hip_runtime.h>

typedef _Float16 f16;
typedef _Float16 f16x2 __attribute__((ext_vector_type(2)));
typedef _Float16 f16x4 __attribute__((ext_vector_type(4)));
typedef _Float16 f16x8 __attribute__((ext_vector_type(8)));
typedef float    f32x4 __attribute__((ext_vector_type(4)));
typedef unsigned int u32;
typedef u32      u32x2 __attribute__((ext_vector_type(2)));
typedef u32      u32x4 __attribute__((ext_vector_type(4)));

#define MFMA32(a, b, c) __builtin_amdgcn_mfma_f32_16x16x32_f16((a), (b), (c), 0, 0, 0)
// NOTE: legacy K=16 intrinsic has NO underscore before f16 on gfx950
#define MFMA16(a, b, c) __builtin_amdgcn_mfma_f32_16x16x16f16((a), (b), (c), 0, 0, 0)

__device__ __forceinline__ float leaky(float x) {
    return fmaf(0.4f, __builtin_fabsf(x), 0.6f * x);
}
__device__ __forceinline__ u32 pkrtz(float a, float b) {
    return __builtin_bit_cast(u32, __builtin_amdgcn_cvt_pkrtz(a, b));
}
// pack 2 f32 -> f16 pair, then leaky in PACKED f16 math (pk_max/pk_min/
// pk_fma = 3 ops/2elem + pkrtz, vs 5 in f32). max/min form keeps positive
// values exact; only the negative branch sees f16-0.2 (2.4e-4 rel).
__device__ __forceinline__ u32 lk_pk2(float a, float b) {
    f16x2 v = __builtin_bit_cast(f16x2, __builtin_amdgcn_cvt_pkrtz(a, b));
    f16x2 z2 = {(f16)0.0f, (f16)0.0f};
    f16x2 mx = __builtin_elementwise_max(v, z2);
    f16x2 mn = __builtin_elementwise_min(v, z2);
    f16x2 r = mn * (f16x2){(f16)0.2f, (f16)0.2f} + mx;
    return __builtin_bit_cast(u32, r);
}
__device__ __forceinline__ f16x4 lk_pk4(const f32x4 z) {
    return __builtin_bit_cast(f16x4, (u32x2){ lk_pk2(z[0], z[1]), lk_pk2(z[2], z[3]) });
}
__device__ __forceinline__ f16x4 pk4(const f32x4 z) {
    return __builtin_bit_cast(f16x4, (u32x2){ pkrtz(z[0], z[1]), pkrtz(z[2], z[3]) });
}
__device__ __forceinline__ void st_lk4(void* p, const f32x4 z) {
    *(u32x2*)p = (u32x2){ lk_pk2(z[0], z[1]), lk_pk2(z[2], z[3]) };
}

// ---------------------------------------------------------------------------
// Prepack: f16 MFMA fragments in d_ws (unchanged).
// ---------------------------------------------------------------------------
__global__ void disc_prepack(const float* __restrict__ Wp1, const float* __restrict__ Wp2,
                             const float* __restrict__ Wn1, const float* __restrict__ Wn2,
                             const float* __restrict__ Wl1, const float* __restrict__ Wl2,
                             f16* __restrict__ ws)
{
    int idx = blockIdx.x * 256 + threadIdx.x;
    if (idx >= 84 * 512 + 24 * 256) return;
    float v = 0.0f;
    if (idx < 84 * 512) {
        int f = idx >> 9, r = idx & 511;
        int lane = r >> 3, e = r & 7;
        int m15 = lane & 15, h = lane >> 4;
        if (f < 64) {
            int mt4 = f >> 4, ks4 = f & 15;
            int k = ks4 * 32 + h * 8 + e;
            v = Wl1[k * 64 + mt4 * 16 + m15];
        } else if (f < 72) {
            int q = f - 64, c = q >> 2, mt = q & 3;
            const float* W1 = c ? Wn1 : Wp1;
            v = (lane < 16) ? W1[e * 64 + mt * 16 + m15] : 0.0f;
        } else if (f < 80) {
            int q = f - 72, c = q >> 2, nt2 = (q >> 1) & 1, ks2 = q & 1;
            const float* W2 = c ? Wn2 : Wp2;
            int k = ks2 * 32 + h * 8 + e;
            v = W2[k * 32 + nt2 * 16 + m15];
        } else {
            int q = f - 80, ms5 = q >> 1, ks5 = q & 1;
            int k = ks5 * 32 + h * 8 + e;
            v = Wl2[k * 32 + ms5 * 16 + m15];
        }
    } else {
        int r2 = idx - 84 * 512;
        int f2 = r2 >> 8, rr = r2 & 255;
        int lane = rr >> 2, e = rr & 3;
        int m15 = lane & 15, h = lane >> 4;
        if (f2 < 16) {
            int c = f2 >> 3, kb = (f2 >> 1) & 3, nt = f2 & 1;
            const float* W2 = c ? Wn2 : Wp2;
            v = W2[(kb * 16 + h * 4 + e) * 32 + nt * 16 + m15];
        } else {
            int q = f2 - 16, kb = q >> 1, nt = q & 1;
            v = Wl2[(kb * 16 + h * 4 + e) * 32 + nt * 16 + m15];
        }
    }
    ws[idx] = (f16)v;
}

// ---------------------------------------------------------------------------
// R15: R14's 4-wave work-split, but __launch_bounds__(256, 4).
//   R14 POST-MORTEM: (256,8) capped the unified reg file at 64/wave; with
//   the MFMA accumulators claiming an aligned AGPR chunk, allocatable VGPRs
//   fell to 32 (rocprof: VGPR_Count=32) and Phase B's ~100-reg live set
//   spilled to scratch -> WRITE_SIZE 512KB -> 434MB, dur 55 -> 235us.
//   Fix: min-waves 4 -> reg cap 128. Natural demand ~64-90 regs, so the
//   HW settles at 6-8 waves/SIMD from ACTUAL usage with zero scratch.
//   wave = (c = wid>>1, half = wid&1). Each wave runs Phase A/B for its
//   channel's batch-half (t in [4*half,4*half+4), 2 interleaved streams),
//   then Phase C over its K-quarter. Total MFMA per block same as R13;
//   per-wave serial chain halved; LDS/block 20480 B.
// LDS layout: [0,4096) Albuf per wave (1 KB each, private);
//             [4096,12288) xbuf ch0; [12288,20480) xbuf ch1;
//             xchg = [0,12288) reused post-C for 3x4KB partials.
// ---------------------------------------------------------------------------
__global__ __launch_bounds__(256, 4) void disc_main(
    const float* __restrict__ adj,
    const float* __restrict__ bp1, const float* __restrict__ bp2,
    const float* __restrict__ bn1, const float* __restrict__ bn2,
    const float* __restrict__ bl1, const float* __restrict__ bl2,
    const float* __restrict__ bl3, const float* __restrict__ Wl3,
    const f16* __restrict__ ws, float* __restrict__ out)
{
    extern __shared__ char smem[];
    const int tid  = threadIdx.x;
    const int lane = tid & 63;
    const int wid  = tid >> 6;
    const int c    = wid >> 1;      // channel this wave owns
    const int half = wid & 1;       // batch-half (A/B) and K-quarter (C)
    const int h    = lane >> 4;
    const int m15  = lane & 15;
    const int i7   = lane & 7;
    const int r8   = m15 >> 3;

    const f16x8* wsf = (const f16x8*)ws;
    const f16x4* wsq = (const f16x4*)(ws + 84 * 512);   // 16x16x16 B-frags

    // ---- this wave's channel weights/biases (runtime c in addresses only) --
    const f16x8* w1p = wsf + (64 + c * 4) * 64 + lane;
    f16x8 w1t0 = w1p[0], w1t1 = w1p[64], w1t2 = w1p[128], w1t3 = w1p[192];
    const f16x4* w2p = wsq + (c * 8) * 64 + lane;
    f16x4 w2k00 = w2p[0],   w2k01 = w2p[64];    // kb=0, nt=0/1
    f16x4 w2k10 = w2p[128], w2k11 = w2p[192];   // kb=1
    f16x4 w2k20 = w2p[256], w2k21 = w2p[320];   // kb=2
    f16x4 w2k30 = w2p[384], w2k31 = w2p[448];   // kb=3
    const f32x4* b1p = (const f32x4*)(c ? bn1 : bp1);
    f32x4 b10 = b1p[h], b11 = b1p[4 + h], b12 = b1p[8 + h], b13 = b1p[12 + h];
    const f32x4* b2p = (const f32x4*)(c ? bn2 : bp2);
    f32x4 b20 = b2p[h], b21 = b2p[4 + h];

    char* Albuf = smem + wid * 1024;            // wave-private, 64 rows x 16 B
    char* xbuf  = smem + 4096 + c * 8192;       // per-channel 8 KB (8 x 1KB frags)
    char* xchg  = smem;                          // 12 KB exchange (dead post-C)

    const long b0 = (long)blockIdx.x * 16;
    const int rxor = ((m15 >> 1) & 3) << 4;
    const bool bsel = ((h >> 1) == r8);    // s3 B-frag block-diag gate
    const int  hlow = h & 1;               // s3 B-frag row-half select
    f32x4 zero4 = {0.0f, 0.0f, 0.0f, 0.0f};
    f16x4 zf4 = {};

    // ---- Phase A: load this wave's 64 adj rows, normalize, stage ----
    {
        const int rid = half * 64 + lane;      // global rid = batch*8 + noderow
        const f32x4* rp = (const f32x4*)(adj + (b0 + (rid >> 3)) * 128 + c * 64 + (rid & 7) * 8);
        f32x4 a0 = rp[0];
        f32x4 a1 = rp[1];
        float s = ((a0[0] + a0[1]) + (a0[2] + a0[3])) + ((a1[0] + a1[1]) + (a1[2] + a1[3]));
        float rv = (s > 0.0f) ? __builtin_amdgcn_rcpf(s) : 0.0f;
        f16x8 row;
        row[0] = (f16)(a0[0] * rv); row[1] = (f16)(a0[1] * rv);
        row[2] = (f16)(a0[2] * rv); row[3] = (f16)(a0[3] * rv);
        row[4] = (f16)(a1[0] * rv); row[5] = (f16)(a1[1] * rv);
        row[6] = (f16)(a1[2] * rv); row[7] = (f16)(a1[3] * rv);
        *(f16x8*)(Albuf + lane * 16) = row;    // local row = lane
    }

    // ---- Phase B: fused GCN, TWO independent t-streams (tla=tp, tlb=tp+2) --
    #pragma unroll 1
    for (int tp = 0; tp < 2; ++tp) {
        const int tla = tp, tlb = tp + 2;            // local t (Albuf rows)
        const int ta = half * 4 + tla;               // global t (xbuf rows)
        const int tb = half * 4 + tlb;
        f16x8 arow_a = *(const f16x8*)(Albuf + (((2 * tla + r8) * 8 + i7) << 4));
        f16x8 arow_b = *(const f16x8*)(Albuf + (((2 * tlb + r8) * 8 + i7) << 4));

        // s1 both: z^T = W1^T @ A^T + b1 (16x16x32, K=8 pad)
        f32x4 z0a = MFMA32(w1t0, arow_a, b10);
        f32x4 z1a = MFMA32(w1t1, arow_a, b11);
        f32x4 z2a = MFMA32(w1t2, arow_a, b12);
        f32x4 z3a = MFMA32(w1t3, arow_a, b13);
        f32x4 z0b = MFMA32(w1t0, arow_b, b10);
        f32x4 z1b = MFMA32(w1t1, arow_b, b11);
        f32x4 z2b = MFMA32(w1t2, arow_b, b12);
        f32x4 z3b = MFMA32(w1t3, arow_b, b13);

        // s1 -> s2: register pack+leaky (packed f16 math)
        f16x4 xa0 = lk_pk4(z0a), xa1 = lk_pk4(z1a), xa2 = lk_pk4(z2a), xa3 = lk_pk4(z3a);
        f16x4 xb0 = lk_pk4(z0b), xb1 = lk_pk4(z1b), xb2 = lk_pk4(z2b), xb3 = lk_pk4(z3b);

        // s2 both: y_nt = sum_kb x1 @ W2 (4-chain of 16x16x16, 4 indep chains)
        f32x4 y0a = MFMA16(xa0, w2k00, zero4);
        f32x4 y1a = MFMA16(xa0, w2k01, zero4);
        f32x4 y0b = MFMA16(xb0, w2k00, zero4);
        f32x4 y1b = MFMA16(xb0, w2k01, zero4);
        y0a = MFMA16(xa1, w2k10, y0a);
        y1a = MFMA16(xa1, w2k11, y1a);
        y0b = MFMA16(xb1, w2k10, y0b);
        y1b = MFMA16(xb1, w2k11, y1b);
        y0a = MFMA16(xa2, w2k20, y0a);
        y1a = MFMA16(xa2, w2k21, y1a);
        y0b = MFMA16(xb2, w2k20, y0b);
        y1b = MFMA16(xb2, w2k21, y1b);
        y0a = MFMA16(xa3, w2k30, y0a);
        y1a = MFMA16(xa3, w2k31, y1a);
        y0b = MFMA16(xb3, w2k30, y0b);
        y1b = MFMA16(xb3, w2k31, y1b);

        // s2 -> s3: register pkrtz; B-frag from arow select (block-diag)
        f16x4 pa0 = pk4(y0a), pa1 = pk4(y1a);
        f16x4 pb0 = pk4(y0b), pb1 = pk4(y1b);
        u32x4 ara = __builtin_bit_cast(u32x4, arow_a);
        u32x4 arb = __builtin_bit_cast(u32x4, arow_b);
        f16x4 halfa = __builtin_bit_cast(f16x4,
            hlow ? (u32x2){ara[2], ara[3]} : (u32x2){ara[0], ara[1]});
        f16x4 halfb = __builtin_bit_cast(f16x4,
            hlow ? (u32x2){arb[2], arb[3]} : (u32x2){arb[0], arb[1]});
        f16x4 bfra = bsel ? halfa : zf4;
        f16x4 bfrb = bsel ? halfb : zf4;

        // s3 both: x2^T = y^T @ BD_A^T + b2 (16x16x16, K=16 exact)
        f32x4 x2aa = MFMA16(pa0, bfra, b20);
        f32x4 x2ba = MFMA16(pa1, bfra, b21);
        f32x4 x2ab = MFMA16(pb0, bfrb, b20);
        f32x4 x2bb = MFMA16(pb1, bfrb, b21);

        // leaky+pack + swizzled xbuf writes; slot = i7, n = 2t+r8 (global t)
        const int lga = h >> 1;
        const int lgb = (lga + 2) & 3;
        char* fb = xbuf + (i7 << 10);
        {
            int wx = ((ta & 3) ^ i7) << 4;
            int basew = ((2 * ta + r8) << 6) + ((h & 1) << 3);
            st_lk4(fb + ((basew + lga * 16) ^ wx), x2aa);
            st_lk4(fb + ((basew + lgb * 16) ^ wx), x2ba);
        }
        {
            int wx = ((tb & 3) ^ i7) << 4;
            int basew = ((2 * tb + r8) << 6) + ((h & 1) << 3);
            st_lk4(fb + ((basew + lga * 16) ^ wx), x2ab);
            st_lk4(fb + ((basew + lgb * 16) ^ wx), x2bb);
        }
    }

    // both halves of this channel's xbuf must be complete before Phase C
    __syncthreads();

    // ---- Phase C: h1 partial += Wl1^T[K-quarter] @ x^T (K=128, 16x16x32) ---
    f32x4 a40 = zero4, a41 = zero4, a42 = zero4, a43 = zero4;
    if (wid == 0) {
        a40 = ((const f32x4*)bl1)[h];
        a41 = ((const f32x4*)bl1)[4 + h];
        a42 = ((const f32x4*)bl1)[8 + h];
        a43 = ((const f32x4*)bl1)[12 + h];
    }
    __builtin_amdgcn_s_setprio(1);
    const int kbase = half * 4;
    #pragma unroll
    for (int kq = 0; kq < 4; ++kq) {
        const int k8 = kbase + kq;
        int xr = rxor ^ (k8 << 4);
        f16x8 xf = *(const f16x8*)(xbuf + (k8 << 10) + ((m15 * 64 + h * 16) ^ xr));
        const f16x8* wl = wsf + (c * 8 + k8) * 64 + lane;
        a40 = MFMA32(wl[0],    xf, a40);
        a41 = MFMA32(wl[1024], xf, a41);
        a42 = MFMA32(wl[2048], xf, a42);
        a43 = MFMA32(wl[3072], xf, a43);
    }
    __builtin_amdgcn_s_setprio(0);

    // ---- cross-wave partial exchange (waves 1..3 -> wave0) ----
    __syncthreads();                 // all C reads done; xchg may overwrite
    if (wid) {
        char* dst = xchg + (wid - 1) * 4096 + lane * 16;
        *(f32x4*)(dst +    0) = a40;
        *(f32x4*)(dst + 1024) = a41;
        *(f32x4*)(dst + 2048) = a42;
        *(f32x4*)(dst + 3072) = a43;
    }
    __syncthreads();
    if (wid == 0) {
        #pragma unroll
        for (int p = 0; p < 3; ++p) {
            const f32x4* xp = (const f32x4*)(xchg + p * 4096 + lane * 16);
            a40 += xp[0];
            a41 += xp[64];
            a42 += xp[128];
            a43 += xp[192];
        }

        // ---- Phase D: register pack+leaky of h1 (A-frags for E) ----
        f16x4 pd0 = lk_pk4(a40), pd1 = lk_pk4(a41);
        f16x4 pd2 = lk_pk4(a42), pd3 = lk_pk4(a43);

        // ---- Phase E: h2 = h1 @ Wl2 + bl2 (4-chain 16x16x16 per nt) ----
        const f16x4* wl2p = wsq + 16 * 64 + lane;
        f16x4 l200 = wl2p[0],   l201 = wl2p[64];    // kb=0 nt=0/1
        f16x4 l210 = wl2p[128], l211 = wl2p[192];
        f16x4 l220 = wl2p[256], l221 = wl2p[320];
        f16x4 l230 = wl2p[384], l231 = wl2p[448];
        float c0 = bl2[m15], c1 = bl2[m15 + 16];
        f32x4 a50 = {c0, c0, c0, c0};
        f32x4 a51 = {c1, c1, c1, c1};
        a50 = MFMA16(pd0, l200, a50);
        a51 = MFMA16(pd0, l201, a51);
        a50 = MFMA16(pd1, l210, a50);
        a51 = MFMA16(pd1, l211, a51);
        a50 = MFMA16(pd2, l220, a50);
        a51 = MFMA16(pd2, l221, a51);
        a50 = MFMA16(pd3, l230, a50);
        a51 = MFMA16(pd3, l231, a51);

        // ---- Phase F: out[b=4h+r] = sum_l2 leaky(h2) Wl3 + bl3 ----
        float w30 = Wl3[m15], w31 = Wl3[m15 + 16];
        const float bl3s = bl3[0];
        #pragma unroll
        for (int r = 0; r < 4; ++r) {
            float acc = leaky(a50[r]) * w30 + leaky(a51[r]) * w31;
            acc += __shfl_xor(acc, 1);
            acc += __shfl_xor(acc, 2);
            acc += __shfl_xor(acc, 4);
            acc += __shfl_xor(acc, 8);
            if (m15 == 0) out[b0 + h * 4 + r] = acc + bl3s;
        }
    }
}

extern "C" void kernel_launch(void* const* d_in, const int* in_sizes, int n_in,
                              void* d_out, int out_size, void* d_ws, size_t ws_size,
                              hipStream_t stream)
{
    const float* adj  = (const float*)d_in[0];
    const float* Wp1  = (const float*)d_in[1];
    const float* bp1  = (const float*)d_in[2];
    const float* Wp2  = (const float*)d_in[3];
    const float* bp2  = (const float*)d_in[4];
    const float* Wn1  = (const float*)d_in[5];
    const float* bn1  = (const float*)d_in[6];
    const float* Wn2  = (const float*)d_in[7];
    const float* bn2  = (const float*)d_in[8];
    const float* Wl1  = (const float*)d_in[9];
    const float* bl1  = (const float*)d_in[10];
    const float* Wl2  = (const float*)d_in[11];
    const float* bl2  = (const float*)d_in[12];
    const float* Wl3  = (const float*)d_in[13];
    const float* bl3  = (const float*)d_in[14];
    f16* ws = (f16*)d_ws;
    float* out = (float*)d_out;

    // 84*512 + 24*256 = 49152 f16; 192 blocks x 256 threads
    hipLaunchKernelGGL(disc_prepack, dim3(192), dim3(256), 0, stream,
                       Wp1, Wp2, Wn1, Wn2, Wl1, Wl2, ws);

    const int ldsBytes = 20480;  // Albuf 4x1K + xbuf 2x8K; xchg overlaps
    hipFuncSetAttribute(reinterpret_cast<const void*>(disc_main),
                        hipFuncAttributeMaxDynamicSharedMemorySize, ldsBytes);
    hipLaunchKernelGGL(disc_main, dim3(8192), dim3(256), ldsBytes, stream,
                       adj, bp1, bp2, bn1, bn2, bl1, bl2, bl3, Wl3, ws, out);
}

// Round 3
// 54.367 us; speedup vs baseline: 3.2308x; 1.1181x over previous
//
#include <hip/hip_runtime.h>

typedef _Float16 f16;
typedef _Float16 f16x2 __attribute__((ext_vector_type(2)));
typedef _Float16 f16x4 __attribute__((ext_vector_type(4)));
typedef _Float16 f16x8 __attribute__((ext_vector_type(8)));
typedef float    f32x4 __attribute__((ext_vector_type(4)));
typedef unsigned int u32;
typedef u32      u32x2 __attribute__((ext_vector_type(2)));
typedef u32      u32x4 __attribute__((ext_vector_type(4)));

#define MFMA32(a, b, c) __builtin_amdgcn_mfma_f32_16x16x32_f16((a), (b), (c), 0, 0, 0)
// NOTE: legacy K=16 intrinsic has NO underscore before f16 on gfx950
#define MFMA16(a, b, c) __builtin_amdgcn_mfma_f32_16x16x16f16((a), (b), (c), 0, 0, 0)

#define TILES 8   // batch-tiles (of 16) per block; grid = 8192/TILES

__device__ __forceinline__ float leaky(float x) {
    return fmaf(0.4f, __builtin_fabsf(x), 0.6f * x);
}
__device__ __forceinline__ u32 pkrtz(float a, float b) {
    return __builtin_bit_cast(u32, __builtin_amdgcn_cvt_pkrtz(a, b));
}
// pack 2 f32 -> f16 pair, then leaky in PACKED f16 math (pk_max/pk_min/
// pk_fma = 3 ops/2elem + pkrtz, vs 5 in f32). max/min form keeps positive
// values exact; only the negative branch sees f16-0.2 (2.4e-4 rel).
__device__ __forceinline__ u32 lk_pk2(float a, float b) {
    f16x2 v = __builtin_bit_cast(f16x2, __builtin_amdgcn_cvt_pkrtz(a, b));
    f16x2 z2 = {(f16)0.0f, (f16)0.0f};
    f16x2 mx = __builtin_elementwise_max(v, z2);
    f16x2 mn = __builtin_elementwise_min(v, z2);
    f16x2 r = mn * (f16x2){(f16)0.2f, (f16)0.2f} + mx;
    return __builtin_bit_cast(u32, r);
}
__device__ __forceinline__ f16x4 lk_pk4(const f32x4 z) {
    return __builtin_bit_cast(f16x4, (u32x2){ lk_pk2(z[0], z[1]), lk_pk2(z[2], z[3]) });
}
__device__ __forceinline__ f16x4 pk4(const f32x4 z) {
    return __builtin_bit_cast(f16x4, (u32x2){ pkrtz(z[0], z[1]), pkrtz(z[2], z[3]) });
}
__device__ __forceinline__ void st_lk4(void* p, const f32x4 z) {
    *(u32x2*)p = (u32x2){ lk_pk2(z[0], z[1]), lk_pk2(z[2], z[3]) };
}

// ---------------------------------------------------------------------------
// Prepack: f16 MFMA fragments in d_ws (unchanged).
// ---------------------------------------------------------------------------
__global__ void disc_prepack(const float* __restrict__ Wp1, const float* __restrict__ Wp2,
                             const float* __restrict__ Wn1, const float* __restrict__ Wn2,
                             const float* __restrict__ Wl1, const float* __restrict__ Wl2,
                             f16* __restrict__ ws)
{
    int idx = blockIdx.x * 256 + threadIdx.x;
    if (idx >= 84 * 512 + 24 * 256) return;
    float v = 0.0f;
    if (idx < 84 * 512) {
        int f = idx >> 9, r = idx & 511;
        int lane = r >> 3, e = r & 7;
        int m15 = lane & 15, h = lane >> 4;
        if (f < 64) {
            int mt4 = f >> 4, ks4 = f & 15;
            int k = ks4 * 32 + h * 8 + e;
            v = Wl1[k * 64 + mt4 * 16 + m15];
        } else if (f < 72) {
            int q = f - 64, c = q >> 2, mt = q & 3;
            const float* W1 = c ? Wn1 : Wp1;
            v = (lane < 16) ? W1[e * 64 + mt * 16 + m15] : 0.0f;
        } else if (f < 80) {
            int q = f - 72, c = q >> 2, nt2 = (q >> 1) & 1, ks2 = q & 1;
            const float* W2 = c ? Wn2 : Wp2;
            int k = ks2 * 32 + h * 8 + e;
            v = W2[k * 32 + nt2 * 16 + m15];
        } else {
            int q = f - 80, ms5 = q >> 1, ks5 = q & 1;
            int k = ks5 * 32 + h * 8 + e;
            v = Wl2[k * 32 + ms5 * 16 + m15];
        }
    } else {
        int r2 = idx - 84 * 512;
        int f2 = r2 >> 8, rr = r2 & 255;
        int lane = rr >> 2, e = rr & 3;
        int m15 = lane & 15, h = lane >> 4;
        if (f2 < 16) {
            int c = f2 >> 3, kb = (f2 >> 1) & 3, nt = f2 & 1;
            const float* W2 = c ? Wn2 : Wp2;
            v = W2[(kb * 16 + h * 4 + e) * 32 + nt * 16 + m15];
        } else {
            int q = f2 - 16, kb = q >> 1, nt = q & 1;
            v = Wl2[(kb * 16 + h * 4 + e) * 32 + nt * 16 + m15];
        }
    }
    ws[idx] = (f16)v;
}

// ---------------------------------------------------------------------------
// R16: R13's 2-wave structure + TILES=8 batch-tiles per block.
//   R15 POST-MORTEM: occupancy stayed ~33% whether capacity was 16 or 32
//   waves/CU -> capacity is NOT the limiter. Little's law across R13/14/15:
//   completion pinned at ~150 WG/us with resident ~2.7 blocks/CU << cap;
//   R14's 4x-longer blocks pushed occupancy to 77%. The machine is limited
//   by block FEED RATE / per-block overhead, not residency capacity.
//   Fix: 8x fewer, 8x longer blocks (grid 1024). Weight loads amortized
//   over 8 tiles; next tile's adj rows PREFETCHED into registers so HBM
//   latency hides under Phase B/C; per-tile exchange uses write-bar-read-bar
//   on a DEDICATED xchg (no aliasing with wave areas), so wave1 runs ahead
//   into tile t+1 while wave0 does the D/E/F tail.
// LDS: wave areas 2 x 10240 (Albuf 2048 + xbuf 8192) + xchg 4096 = 24576.
// ---------------------------------------------------------------------------
__global__ __launch_bounds__(128, 2) void disc_main(
    const float* __restrict__ adj,
    const float* __restrict__ bp1, const float* __restrict__ bp2,
    const float* __restrict__ bn1, const float* __restrict__ bn2,
    const float* __restrict__ bl1, const float* __restrict__ bl2,
    const float* __restrict__ bl3, const float* __restrict__ Wl3,
    const f16* __restrict__ ws, float* __restrict__ out)
{
    extern __shared__ char smem[];
    const int tid  = threadIdx.x;
    const int lane = tid & 63;
    const int wid  = tid >> 6;      // == channel c this wave owns
    const int h    = lane >> 4;
    const int m15  = lane & 15;
    const int i7   = lane & 7;
    const int r8   = m15 >> 3;

    const f16x8* wsf = (const f16x8*)ws;
    const f16x4* wsq = (const f16x4*)(ws + 84 * 512);   // 16x16x16 B-frags
    const int c = wid;

    // ---- this wave's channel weights/biases (loaded ONCE for all tiles) ---
    const f16x8* w1p = wsf + (64 + c * 4) * 64 + lane;
    f16x8 w1t0 = w1p[0], w1t1 = w1p[64], w1t2 = w1p[128], w1t3 = w1p[192];
    const f16x4* w2p = wsq + (c * 8) * 64 + lane;
    f16x4 w2k00 = w2p[0],   w2k01 = w2p[64];    // kb=0, nt=0/1
    f16x4 w2k10 = w2p[128], w2k11 = w2p[192];   // kb=1
    f16x4 w2k20 = w2p[256], w2k21 = w2p[320];   // kb=2
    f16x4 w2k30 = w2p[384], w2k31 = w2p[448];   // kb=3
    const f32x4* b1p = (const f32x4*)(c ? bn1 : bp1);
    f32x4 b10 = b1p[h], b11 = b1p[4 + h], b12 = b1p[8 + h], b13 = b1p[12 + h];
    const f32x4* b2p = (const f32x4*)(c ? bn2 : bp2);
    f32x4 b20 = b2p[h], b21 = b2p[4 + h];
    f32x4 bl1v0 = ((const f32x4*)bl1)[h],      bl1v1 = ((const f32x4*)bl1)[4 + h];
    f32x4 bl1v2 = ((const f32x4*)bl1)[8 + h],  bl1v3 = ((const f32x4*)bl1)[12 + h];

    // ---- tail weights (wave0 only), hoisted out of the tile loop ----
    f16x4 l200, l201, l210, l211, l220, l221, l230, l231;
    float c0 = 0.0f, c1 = 0.0f, w30 = 0.0f, w31 = 0.0f, bl3s = 0.0f;
    if (wid == 0) {
        const f16x4* wl2p = wsq + 16 * 64 + lane;
        l200 = wl2p[0];   l201 = wl2p[64];
        l210 = wl2p[128]; l211 = wl2p[192];
        l220 = wl2p[256]; l221 = wl2p[320];
        l230 = wl2p[384]; l231 = wl2p[448];
        c0 = bl2[m15]; c1 = bl2[m15 + 16];
        w30 = Wl3[m15]; w31 = Wl3[m15 + 16];
        bl3s = bl3[0];
    }

    char* wbase = smem + wid * 10240;
    char* Albuf = wbase;              // 2048 B
    char* xbuf  = wbase + 2048;       // 8192 B (8 swizzled 1KB frags)
    char* xchg  = smem + 20480;       // 4 KB dedicated exchange

    const int rxor = ((m15 >> 1) & 3) << 4;
    const bool bsel = ((h >> 1) == r8);    // s3 B-frag block-diag gate
    const int  hlow = h & 1;               // s3 B-frag row-half select
    f32x4 zero4 = {0.0f, 0.0f, 0.0f, 0.0f};
    f16x4 zf4 = {};

    long b0 = (long)blockIdx.x * (16 * TILES);

    // ---- prefetch tile 0's raw adj rows into registers ----
    f32x4 c00, c01, c10, c11;
    {
        const f32x4* rp0 = (const f32x4*)(adj + (b0 + (lane >> 3)) * 128 + c * 64 + (lane & 7) * 8);
        c00 = rp0[0]; c01 = rp0[1];
        const int rid1 = 64 + lane;
        const f32x4* rp1 = (const f32x4*)(adj + (b0 + (rid1 >> 3)) * 128 + c * 64 + (rid1 & 7) * 8);
        c10 = rp1[0]; c11 = rp1[1];
    }

    #pragma unroll 1
    for (int it = 0; it < TILES; ++it, b0 += 16) {
        // ---- Phase A: normalize prefetched rows, stage to Albuf ----
        {
            float s = ((c00[0] + c00[1]) + (c00[2] + c00[3])) + ((c01[0] + c01[1]) + (c01[2] + c01[3]));
            float rv = (s > 0.0f) ? __builtin_amdgcn_rcpf(s) : 0.0f;
            f16x8 row;
            row[0] = (f16)(c00[0] * rv); row[1] = (f16)(c00[1] * rv);
            row[2] = (f16)(c00[2] * rv); row[3] = (f16)(c00[3] * rv);
            row[4] = (f16)(c01[0] * rv); row[5] = (f16)(c01[1] * rv);
            row[6] = (f16)(c01[2] * rv); row[7] = (f16)(c01[3] * rv);
            *(f16x8*)(Albuf + lane * 16) = row;
        }
        {
            float s = ((c10[0] + c10[1]) + (c10[2] + c10[3])) + ((c11[0] + c11[1]) + (c11[2] + c11[3]));
            float rv = (s > 0.0f) ? __builtin_amdgcn_rcpf(s) : 0.0f;
            f16x8 row;
            row[0] = (f16)(c10[0] * rv); row[1] = (f16)(c10[1] * rv);
            row[2] = (f16)(c10[2] * rv); row[3] = (f16)(c10[3] * rv);
            row[4] = (f16)(c11[0] * rv); row[5] = (f16)(c11[1] * rv);
            row[6] = (f16)(c11[2] * rv); row[7] = (f16)(c11[3] * rv);
            *(f16x8*)(Albuf + (64 + lane) * 16) = row;
        }

        // ---- prefetch next tile's raw rows (hides HBM under B/C compute) --
        f32x4 n00, n01, n10, n11;
        const bool more = (it + 1 < TILES);
        if (more) {
            const f32x4* rp0 = (const f32x4*)(adj + (b0 + 16 + (lane >> 3)) * 128 + c * 64 + (lane & 7) * 8);
            n00 = rp0[0]; n01 = rp0[1];
            const int rid1 = 64 + lane;
            const f32x4* rp1 = (const f32x4*)(adj + (b0 + 16 + (rid1 >> 3)) * 128 + c * 64 + (rid1 & 7) * 8);
            n10 = rp1[0]; n11 = rp1[1];
        }

        // ---- Phase B: fused GCN, TWO independent t-streams (ta, tb=ta+4) --
        #pragma unroll 1
        for (int tp = 0; tp < 4; ++tp) {
            const int ta = tp, tb = tp + 4;
            f16x8 arow_a = *(const f16x8*)(Albuf + (((2 * ta + r8) * 8 + i7) << 4));
            f16x8 arow_b = *(const f16x8*)(Albuf + (((2 * tb + r8) * 8 + i7) << 4));

            // s1 both: z^T = W1^T @ A^T + b1 (16x16x32, K=8 pad)
            f32x4 z0a = MFMA32(w1t0, arow_a, b10);
            f32x4 z1a = MFMA32(w1t1, arow_a, b11);
            f32x4 z2a = MFMA32(w1t2, arow_a, b12);
            f32x4 z3a = MFMA32(w1t3, arow_a, b13);
            f32x4 z0b = MFMA32(w1t0, arow_b, b10);
            f32x4 z1b = MFMA32(w1t1, arow_b, b11);
            f32x4 z2b = MFMA32(w1t2, arow_b, b12);
            f32x4 z3b = MFMA32(w1t3, arow_b, b13);

            // s1 -> s2: register pack+leaky (packed f16 math)
            f16x4 xa0 = lk_pk4(z0a), xa1 = lk_pk4(z1a), xa2 = lk_pk4(z2a), xa3 = lk_pk4(z3a);
            f16x4 xb0 = lk_pk4(z0b), xb1 = lk_pk4(z1b), xb2 = lk_pk4(z2b), xb3 = lk_pk4(z3b);

            // s2 both: y_nt = sum_kb x1 @ W2 (4-chain of 16x16x16, 4 indep chains)
            f32x4 y0a = MFMA16(xa0, w2k00, zero4);
            f32x4 y1a = MFMA16(xa0, w2k01, zero4);
            f32x4 y0b = MFMA16(xb0, w2k00, zero4);
            f32x4 y1b = MFMA16(xb0, w2k01, zero4);
            y0a = MFMA16(xa1, w2k10, y0a);
            y1a = MFMA16(xa1, w2k11, y1a);
            y0b = MFMA16(xb1, w2k10, y0b);
            y1b = MFMA16(xb1, w2k11, y1b);
            y0a = MFMA16(xa2, w2k20, y0a);
            y1a = MFMA16(xa2, w2k21, y1a);
            y0b = MFMA16(xb2, w2k20, y0b);
            y1b = MFMA16(xb2, w2k21, y1b);
            y0a = MFMA16(xa3, w2k30, y0a);
            y1a = MFMA16(xa3, w2k31, y1a);
            y0b = MFMA16(xb3, w2k30, y0b);
            y1b = MFMA16(xb3, w2k31, y1b);

            // s2 -> s3: register pkrtz; B-frag from arow select (block-diag)
            f16x4 pa0 = pk4(y0a), pa1 = pk4(y1a);
            f16x4 pb0 = pk4(y0b), pb1 = pk4(y1b);
            u32x4 ara = __builtin_bit_cast(u32x4, arow_a);
            u32x4 arb = __builtin_bit_cast(u32x4, arow_b);
            f16x4 halfa = __builtin_bit_cast(f16x4,
                hlow ? (u32x2){ara[2], ara[3]} : (u32x2){ara[0], ara[1]});
            f16x4 halfb = __builtin_bit_cast(f16x4,
                hlow ? (u32x2){arb[2], arb[3]} : (u32x2){arb[0], arb[1]});
            f16x4 bfra = bsel ? halfa : zf4;
            f16x4 bfrb = bsel ? halfb : zf4;

            // s3 both: x2^T = y^T @ BD_A^T + b2 (16x16x16, K=16 exact)
            f32x4 x2aa = MFMA16(pa0, bfra, b20);
            f32x4 x2ba = MFMA16(pa1, bfra, b21);
            f32x4 x2ab = MFMA16(pb0, bfrb, b20);
            f32x4 x2bb = MFMA16(pb1, bfrb, b21);

            // leaky+pack + swizzled xbuf writes; slot = i7, n = 2t+r8
            const int lga = h >> 1;
            const int lgb = (lga + 2) & 3;
            char* fb = xbuf + (i7 << 10);
            {
                int wx = ((ta & 3) ^ i7) << 4;
                int basew = ((2 * ta + r8) << 6) + ((h & 1) << 3);
                st_lk4(fb + ((basew + lga * 16) ^ wx), x2aa);
                st_lk4(fb + ((basew + lgb * 16) ^ wx), x2ba);
            }
            {
                int wx = ((tb & 3) ^ i7) << 4;
                int basew = ((2 * tb + r8) << 6) + ((h & 1) << 3);
                st_lk4(fb + ((basew + lga * 16) ^ wx), x2ab);
                st_lk4(fb + ((basew + lgb * 16) ^ wx), x2bb);
            }
        }

        // ---- Phase C: h1 partial += Wl1^T[k-half c] @ x^T (K=256) ----
        f32x4 a40 = wid ? zero4 : bl1v0;
        f32x4 a41 = wid ? zero4 : bl1v1;
        f32x4 a42 = wid ? zero4 : bl1v2;
        f32x4 a43 = wid ? zero4 : bl1v3;
        __builtin_amdgcn_s_setprio(1);
        #pragma unroll 4
        for (int k8 = 0; k8 < 8; ++k8) {
            int xr = rxor ^ (k8 << 4);
            f16x8 xf = *(const f16x8*)(xbuf + (k8 << 10) + ((m15 * 64 + h * 16) ^ xr));
            const f16x8* wl = wsf + (c * 8 + k8) * 64 + lane;
            a40 = MFMA32(wl[0],    xf, a40);
            a41 = MFMA32(wl[1024], xf, a41);
            a42 = MFMA32(wl[2048], xf, a42);
            a43 = MFMA32(wl[3072], xf, a43);
        }
        __builtin_amdgcn_s_setprio(0);

        // ---- cross-wave partial exchange (wave1 -> wave0, dedicated xchg) --
        if (wid == 1) {
            *(f32x4*)(xchg +    0 + lane * 16) = a40;
            *(f32x4*)(xchg + 1024 + lane * 16) = a41;
            *(f32x4*)(xchg + 2048 + lane * 16) = a42;
            *(f32x4*)(xchg + 3072 + lane * 16) = a43;
        }
        __syncthreads();
        f32x4 p0, p1, p2, p3;
        if (wid == 0) {
            p0 = *(const f32x4*)(xchg +    0 + lane * 16);
            p1 = *(const f32x4*)(xchg + 1024 + lane * 16);
            p2 = *(const f32x4*)(xchg + 2048 + lane * 16);
            p3 = *(const f32x4*)(xchg + 3072 + lane * 16);
        }
        __syncthreads();   // xchg free; wave1 may run ahead into tile t+1

        if (wid == 0) {
            a40 += p0; a41 += p1; a42 += p2; a43 += p3;

            // ---- Phase D: register pack+leaky of h1 (A-frags for E) ----
            f16x4 pd0 = lk_pk4(a40), pd1 = lk_pk4(a41);
            f16x4 pd2 = lk_pk4(a42), pd3 = lk_pk4(a43);

            // ---- Phase E: h2 = h1 @ Wl2 + bl2 (4-chain 16x16x16 per nt) --
            f32x4 a50 = {c0, c0, c0, c0};
            f32x4 a51 = {c1, c1, c1, c1};
            a50 = MFMA16(pd0, l200, a50);
            a51 = MFMA16(pd0, l201, a51);
            a50 = MFMA16(pd1, l210, a50);
            a51 = MFMA16(pd1, l211, a51);
            a50 = MFMA16(pd2, l220, a50);
            a51 = MFMA16(pd2, l221, a51);
            a50 = MFMA16(pd3, l230, a50);
            a51 = MFMA16(pd3, l231, a51);

            // ---- Phase F: out[b=4h+r] = sum_l2 leaky(h2) Wl3 + bl3 ----
            #pragma unroll
            for (int r = 0; r < 4; ++r) {
                float acc = leaky(a50[r]) * w30 + leaky(a51[r]) * w31;
                acc += __shfl_xor(acc, 1);
                acc += __shfl_xor(acc, 2);
                acc += __shfl_xor(acc, 4);
                acc += __shfl_xor(acc, 8);
                if (m15 == 0) out[b0 + h * 4 + r] = acc + bl3s;
            }
        }

        // ---- rotate prefetched rows ----
        if (more) { c00 = n00; c01 = n01; c10 = n10; c11 = n11; }
    }
}

extern "C" void kernel_launch(void* const* d_in, const int* in_sizes, int n_in,
                              void* d_out, int out_size, void* d_ws, size_t ws_size,
                              hipStream_t stream)
{
    const float* adj  = (const float*)d_in[0];
    const float* Wp1  = (const float*)d_in[1];
    const float* bp1  = (const float*)d_in[2];
    const float* Wp2  = (const float*)d_in[3];
    const float* bp2  = (const float*)d_in[4];
    const float* Wn1  = (const float*)d_in[5];
    const float* bn1  = (const float*)d_in[6];
    const float* Wn2  = (const float*)d_in[7];
    const float* bn2  = (const float*)d_in[8];
    const float* Wl1  = (const float*)d_in[9];
    const float* bl1  = (const float*)d_in[10];
    const float* Wl2  = (const float*)d_in[11];
    const float* bl2  = (const float*)d_in[12];
    const float* Wl3  = (const float*)d_in[13];
    const float* bl3  = (const float*)d_in[14];
    f16* ws = (f16*)d_ws;
    float* out = (float*)d_out;

    // 84*512 + 24*256 = 49152 f16; 192 blocks x 256 threads
    hipLaunchKernelGGL(disc_prepack, dim3(192), dim3(256), 0, stream,
                       Wp1, Wp2, Wn1, Wn2, Wl1, Wl2, ws);

    const int ldsBytes = 24576;  // 2 x 10240 wave areas + 4096 xchg
    hipFuncSetAttribute(reinterpret_cast<const void*>(disc_main),
                        hipFuncAttributeMaxDynamicSharedMemorySize, ldsBytes);
    hipLaunchKernelGGL(disc_main, dim3(8192 / TILES), dim3(128), ldsBytes, stream,
                       adj, bp1, bp2, bn1, bn2, bl1, bl2, bl3, Wl3, ws, out);
}

// Round 4
// 53.616 us; speedup vs baseline: 3.2760x; 1.0140x over previous
//
#include <hip/hip_runtime.h>

typedef _Float16 f16;
typedef _Float16 f16x2 __attribute__((ext_vector_type(2)));
typedef _Float16 f16x4 __attribute__((ext_vector_type(4)));
typedef _Float16 f16x8 __attribute__((ext_vector_type(8)));
typedef float    f32x4 __attribute__((ext_vector_type(4)));
typedef unsigned int u32;
typedef u32      u32x2 __attribute__((ext_vector_type(2)));
typedef u32      u32x4 __attribute__((ext_vector_type(4)));

#define MFMA32(a, b, c) __builtin_amdgcn_mfma_f32_16x16x32_f16((a), (b), (c), 0, 0, 0)
// NOTE: legacy K=16 intrinsic has NO underscore before f16 on gfx950
#define MFMA16(a, b, c) __builtin_amdgcn_mfma_f32_16x16x16f16((a), (b), (c), 0, 0, 0)

#define TILES 8   // batch-tiles (of 16) per block; grid = 8192/TILES

__device__ __forceinline__ float leaky(float x) {
    return fmaf(0.4f, __builtin_fabsf(x), 0.6f * x);
}
__device__ __forceinline__ u32 pkrtz(float a, float b) {
    return __builtin_bit_cast(u32, __builtin_amdgcn_cvt_pkrtz(a, b));
}
// pack 2 f32 -> f16 pair, then leaky in PACKED f16 math (pk_max/pk_min/
// pk_fma = 3 ops/2elem + pkrtz, vs 5 in f32). max/min form keeps positive
// values exact; only the negative branch sees f16-0.2 (2.4e-4 rel).
__device__ __forceinline__ u32 lk_pk2(float a, float b) {
    f16x2 v = __builtin_bit_cast(f16x2, __builtin_amdgcn_cvt_pkrtz(a, b));
    f16x2 z2 = {(f16)0.0f, (f16)0.0f};
    f16x2 mx = __builtin_elementwise_max(v, z2);
    f16x2 mn = __builtin_elementwise_min(v, z2);
    f16x2 r = mn * (f16x2){(f16)0.2f, (f16)0.2f} + mx;
    return __builtin_bit_cast(u32, r);
}
__device__ __forceinline__ f16x4 lk_pk4(const f32x4 z) {
    return __builtin_bit_cast(f16x4, (u32x2){ lk_pk2(z[0], z[1]), lk_pk2(z[2], z[3]) });
}
__device__ __forceinline__ f16x4 pk4(const f32x4 z) {
    return __builtin_bit_cast(f16x4, (u32x2){ pkrtz(z[0], z[1]), pkrtz(z[2], z[3]) });
}
__device__ __forceinline__ void st_lk4(void* p, const f32x4 z) {
    *(u32x2*)p = (u32x2){ lk_pk2(z[0], z[1]), lk_pk2(z[2], z[3]) };
}

// ---------------------------------------------------------------------------
// Prepack: f16 MFMA fragments in d_ws (unchanged).
// ---------------------------------------------------------------------------
__global__ void disc_prepack(const float* __restrict__ Wp1, const float* __restrict__ Wp2,
                             const float* __restrict__ Wn1, const float* __restrict__ Wn2,
                             const float* __restrict__ Wl1, const float* __restrict__ Wl2,
                             f16* __restrict__ ws)
{
    int idx = blockIdx.x * 256 + threadIdx.x;
    if (idx >= 84 * 512 + 24 * 256) return;
    float v = 0.0f;
    if (idx < 84 * 512) {
        int f = idx >> 9, r = idx & 511;
        int lane = r >> 3, e = r & 7;
        int m15 = lane & 15, h = lane >> 4;
        if (f < 64) {
            int mt4 = f >> 4, ks4 = f & 15;
            int k = ks4 * 32 + h * 8 + e;
            v = Wl1[k * 64 + mt4 * 16 + m15];
        } else if (f < 72) {
            int q = f - 64, c = q >> 2, mt = q & 3;
            const float* W1 = c ? Wn1 : Wp1;
            v = (lane < 16) ? W1[e * 64 + mt * 16 + m15] : 0.0f;
        } else if (f < 80) {
            int q = f - 72, c = q >> 2, nt2 = (q >> 1) & 1, ks2 = q & 1;
            const float* W2 = c ? Wn2 : Wp2;
            int k = ks2 * 32 + h * 8 + e;
            v = W2[k * 32 + nt2 * 16 + m15];
        } else {
            int q = f - 80, ms5 = q >> 1, ks5 = q & 1;
            int k = ks5 * 32 + h * 8 + e;
            v = Wl2[k * 32 + ms5 * 16 + m15];
        }
    } else {
        int r2 = idx - 84 * 512;
        int f2 = r2 >> 8, rr = r2 & 255;
        int lane = rr >> 2, e = rr & 3;
        int m15 = lane & 15, h = lane >> 4;
        if (f2 < 16) {
            int c = f2 >> 3, kb = (f2 >> 1) & 3, nt = f2 & 1;
            const float* W2 = c ? Wn2 : Wp2;
            v = W2[(kb * 16 + h * 4 + e) * 32 + nt * 16 + m15];
        } else {
            int q = f2 - 16, kb = q >> 1, nt = q & 1;
            v = Wl2[(kb * 16 + h * 4 + e) * 32 + nt * 16 + m15];
        }
    }
    ws[idx] = (f16)v;
}

// ---------------------------------------------------------------------------
// R17: R16 shell + issue-ILP attack.
//   R16 POST-MORTEM: grid was nearly fully co-resident (19% occ = ~6
//   waves/CU vs 8 provided); perf invariant from 6..10.7 waves/CU =>
//   NOT wave-starved; per-SIMD issue is saturated by VALU (busy-time
//   ~24us of 54) + MFMA (15us) + bubbles from the 2-stream dependency
//   chain. Fixes:
//   (1) tp loop unroll 2 -> FOUR independent Phase-B streams per wave
//       (ILP bought with registers; VGPR 108 -> ~180, cap 256).
//   (2) single barrier per tile via double-buffered xchg (it&1).
//   (3) Phase A packs rows with 4 pkrtz instead of 8 scalar cvt.
// LDS: 2 x 10240 wave areas + 2 x 4096 xchg = 28672.
// ---------------------------------------------------------------------------
__global__ __launch_bounds__(128, 2) void disc_main(
    const float* __restrict__ adj,
    const float* __restrict__ bp1, const float* __restrict__ bp2,
    const float* __restrict__ bn1, const float* __restrict__ bn2,
    const float* __restrict__ bl1, const float* __restrict__ bl2,
    const float* __restrict__ bl3, const float* __restrict__ Wl3,
    const f16* __restrict__ ws, float* __restrict__ out)
{
    extern __shared__ char smem[];
    const int tid  = threadIdx.x;
    const int lane = tid & 63;
    const int wid  = tid >> 6;      // == channel c this wave owns
    const int h    = lane >> 4;
    const int m15  = lane & 15;
    const int i7   = lane & 7;
    const int r8   = m15 >> 3;

    const f16x8* wsf = (const f16x8*)ws;
    const f16x4* wsq = (const f16x4*)(ws + 84 * 512);   // 16x16x16 B-frags
    const int c = wid;

    // ---- this wave's channel weights/biases (loaded ONCE for all tiles) ---
    const f16x8* w1p = wsf + (64 + c * 4) * 64 + lane;
    f16x8 w1t0 = w1p[0], w1t1 = w1p[64], w1t2 = w1p[128], w1t3 = w1p[192];
    const f16x4* w2p = wsq + (c * 8) * 64 + lane;
    f16x4 w2k00 = w2p[0],   w2k01 = w2p[64];    // kb=0, nt=0/1
    f16x4 w2k10 = w2p[128], w2k11 = w2p[192];   // kb=1
    f16x4 w2k20 = w2p[256], w2k21 = w2p[320];   // kb=2
    f16x4 w2k30 = w2p[384], w2k31 = w2p[448];   // kb=3
    const f32x4* b1p = (const f32x4*)(c ? bn1 : bp1);
    f32x4 b10 = b1p[h], b11 = b1p[4 + h], b12 = b1p[8 + h], b13 = b1p[12 + h];
    const f32x4* b2p = (const f32x4*)(c ? bn2 : bp2);
    f32x4 b20 = b2p[h], b21 = b2p[4 + h];
    f32x4 bl1v0 = ((const f32x4*)bl1)[h],      bl1v1 = ((const f32x4*)bl1)[4 + h];
    f32x4 bl1v2 = ((const f32x4*)bl1)[8 + h],  bl1v3 = ((const f32x4*)bl1)[12 + h];

    // ---- tail weights (wave0 only), hoisted out of the tile loop ----
    f16x4 l200, l201, l210, l211, l220, l221, l230, l231;
    float c0 = 0.0f, c1 = 0.0f, w30 = 0.0f, w31 = 0.0f, bl3s = 0.0f;
    if (wid == 0) {
        const f16x4* wl2p = wsq + 16 * 64 + lane;
        l200 = wl2p[0];   l201 = wl2p[64];
        l210 = wl2p[128]; l211 = wl2p[192];
        l220 = wl2p[256]; l221 = wl2p[320];
        l230 = wl2p[384]; l231 = wl2p[448];
        c0 = bl2[m15]; c1 = bl2[m15 + 16];
        w30 = Wl3[m15]; w31 = Wl3[m15 + 16];
        bl3s = bl3[0];
    }

    char* wbase = smem + wid * 10240;
    char* Albuf = wbase;              // 2048 B
    char* xbuf  = wbase + 2048;       // 8192 B (8 swizzled 1KB frags)

    const int rxor = ((m15 >> 1) & 3) << 4;
    const bool bsel = ((h >> 1) == r8);    // s3 B-frag block-diag gate
    const int  hlow = h & 1;               // s3 B-frag row-half select
    f32x4 zero4 = {0.0f, 0.0f, 0.0f, 0.0f};
    f16x4 zf4 = {};

    long b0 = (long)blockIdx.x * (16 * TILES);

    // ---- prefetch tile 0's raw adj rows into registers ----
    f32x4 c00, c01, c10, c11;
    {
        const f32x4* rp0 = (const f32x4*)(adj + (b0 + (lane >> 3)) * 128 + c * 64 + (lane & 7) * 8);
        c00 = rp0[0]; c01 = rp0[1];
        const int rid1 = 64 + lane;
        const f32x4* rp1 = (const f32x4*)(adj + (b0 + (rid1 >> 3)) * 128 + c * 64 + (rid1 & 7) * 8);
        c10 = rp1[0]; c11 = rp1[1];
    }

    #pragma unroll 1
    for (int it = 0; it < TILES; ++it, b0 += 16) {
        // ---- Phase A: normalize prefetched rows, stage to Albuf ----
        {
            float s = ((c00[0] + c00[1]) + (c00[2] + c00[3])) + ((c01[0] + c01[1]) + (c01[2] + c01[3]));
            float rv = (s > 0.0f) ? __builtin_amdgcn_rcpf(s) : 0.0f;
            u32x4 row = { pkrtz(c00[0] * rv, c00[1] * rv), pkrtz(c00[2] * rv, c00[3] * rv),
                          pkrtz(c01[0] * rv, c01[1] * rv), pkrtz(c01[2] * rv, c01[3] * rv) };
            *(u32x4*)(Albuf + lane * 16) = row;
        }
        {
            float s = ((c10[0] + c10[1]) + (c10[2] + c10[3])) + ((c11[0] + c11[1]) + (c11[2] + c11[3]));
            float rv = (s > 0.0f) ? __builtin_amdgcn_rcpf(s) : 0.0f;
            u32x4 row = { pkrtz(c10[0] * rv, c10[1] * rv), pkrtz(c10[2] * rv, c10[3] * rv),
                          pkrtz(c11[0] * rv, c11[1] * rv), pkrtz(c11[2] * rv, c11[3] * rv) };
            *(u32x4*)(Albuf + (64 + lane) * 16) = row;
        }

        // ---- prefetch next tile's raw rows (hides HBM under B/C compute) --
        f32x4 n00, n01, n10, n11;
        const bool more = (it + 1 < TILES);
        if (more) {
            const f32x4* rp0 = (const f32x4*)(adj + (b0 + 16 + (lane >> 3)) * 128 + c * 64 + (lane & 7) * 8);
            n00 = rp0[0]; n01 = rp0[1];
            const int rid1 = 64 + lane;
            const f32x4* rp1 = (const f32x4*)(adj + (b0 + 16 + (rid1 >> 3)) * 128 + c * 64 + (rid1 & 7) * 8);
            n10 = rp1[0]; n11 = rp1[1];
        }

        // ---- Phase B: fused GCN, FOUR independent t-streams (unroll 2) ----
        #pragma unroll 2
        for (int tp = 0; tp < 4; ++tp) {
            const int ta = tp, tb = tp + 4;
            f16x8 arow_a = *(const f16x8*)(Albuf + (((2 * ta + r8) * 8 + i7) << 4));
            f16x8 arow_b = *(const f16x8*)(Albuf + (((2 * tb + r8) * 8 + i7) << 4));

            // s1 both: z^T = W1^T @ A^T + b1 (16x16x32, K=8 pad)
            f32x4 z0a = MFMA32(w1t0, arow_a, b10);
            f32x4 z1a = MFMA32(w1t1, arow_a, b11);
            f32x4 z2a = MFMA32(w1t2, arow_a, b12);
            f32x4 z3a = MFMA32(w1t3, arow_a, b13);
            f32x4 z0b = MFMA32(w1t0, arow_b, b10);
            f32x4 z1b = MFMA32(w1t1, arow_b, b11);
            f32x4 z2b = MFMA32(w1t2, arow_b, b12);
            f32x4 z3b = MFMA32(w1t3, arow_b, b13);

            // s1 -> s2: register pack+leaky (packed f16 math)
            f16x4 xa0 = lk_pk4(z0a), xa1 = lk_pk4(z1a), xa2 = lk_pk4(z2a), xa3 = lk_pk4(z3a);
            f16x4 xb0 = lk_pk4(z0b), xb1 = lk_pk4(z1b), xb2 = lk_pk4(z2b), xb3 = lk_pk4(z3b);

            // s2 both: y_nt = sum_kb x1 @ W2 (4-chain of 16x16x16, 4 indep chains)
            f32x4 y0a = MFMA16(xa0, w2k00, zero4);
            f32x4 y1a = MFMA16(xa0, w2k01, zero4);
            f32x4 y0b = MFMA16(xb0, w2k00, zero4);
            f32x4 y1b = MFMA16(xb0, w2k01, zero4);
            y0a = MFMA16(xa1, w2k10, y0a);
            y1a = MFMA16(xa1, w2k11, y1a);
            y0b = MFMA16(xb1, w2k10, y0b);
            y1b = MFMA16(xb1, w2k11, y1b);
            y0a = MFMA16(xa2, w2k20, y0a);
            y1a = MFMA16(xa2, w2k21, y1a);
            y0b = MFMA16(xb2, w2k20, y0b);
            y1b = MFMA16(xb2, w2k21, y1b);
            y0a = MFMA16(xa3, w2k30, y0a);
            y1a = MFMA16(xa3, w2k31, y1a);
            y0b = MFMA16(xb3, w2k30, y0b);
            y1b = MFMA16(xb3, w2k31, y1b);

            // s2 -> s3: register pkrtz; B-frag from arow select (block-diag)
            f16x4 pa0 = pk4(y0a), pa1 = pk4(y1a);
            f16x4 pb0 = pk4(y0b), pb1 = pk4(y1b);
            u32x4 ara = __builtin_bit_cast(u32x4, arow_a);
            u32x4 arb = __builtin_bit_cast(u32x4, arow_b);
            f16x4 halfa = __builtin_bit_cast(f16x4,
                hlow ? (u32x2){ara[2], ara[3]} : (u32x2){ara[0], ara[1]});
            f16x4 halfb = __builtin_bit_cast(f16x4,
                hlow ? (u32x2){arb[2], arb[3]} : (u32x2){arb[0], arb[1]});
            f16x4 bfra = bsel ? halfa : zf4;
            f16x4 bfrb = bsel ? halfb : zf4;

            // s3 both: x2^T = y^T @ BD_A^T + b2 (16x16x16, K=16 exact)
            f32x4 x2aa = MFMA16(pa0, bfra, b20);
            f32x4 x2ba = MFMA16(pa1, bfra, b21);
            f32x4 x2ab = MFMA16(pb0, bfrb, b20);
            f32x4 x2bb = MFMA16(pb1, bfrb, b21);

            // leaky+pack + swizzled xbuf writes; slot = i7, n = 2t+r8
            const int lga = h >> 1;
            const int lgb = (lga + 2) & 3;
            char* fb = xbuf + (i7 << 10);
            {
                int wx = ((ta & 3) ^ i7) << 4;
                int basew = ((2 * ta + r8) << 6) + ((h & 1) << 3);
                st_lk4(fb + ((basew + lga * 16) ^ wx), x2aa);
                st_lk4(fb + ((basew + lgb * 16) ^ wx), x2ba);
            }
            {
                int wx = ((tb & 3) ^ i7) << 4;
                int basew = ((2 * tb + r8) << 6) + ((h & 1) << 3);
                st_lk4(fb + ((basew + lga * 16) ^ wx), x2ab);
                st_lk4(fb + ((basew + lgb * 16) ^ wx), x2bb);
            }
        }

        // ---- Phase C: h1 partial += Wl1^T[k-half c] @ x^T (K=256) ----
        f32x4 a40 = wid ? zero4 : bl1v0;
        f32x4 a41 = wid ? zero4 : bl1v1;
        f32x4 a42 = wid ? zero4 : bl1v2;
        f32x4 a43 = wid ? zero4 : bl1v3;
        __builtin_amdgcn_s_setprio(1);
        #pragma unroll 4
        for (int k8 = 0; k8 < 8; ++k8) {
            int xr = rxor ^ (k8 << 4);
            f16x8 xf = *(const f16x8*)(xbuf + (k8 << 10) + ((m15 * 64 + h * 16) ^ xr));
            const f16x8* wl = wsf + (c * 8 + k8) * 64 + lane;
            a40 = MFMA32(wl[0],    xf, a40);
            a41 = MFMA32(wl[1024], xf, a41);
            a42 = MFMA32(wl[2048], xf, a42);
            a43 = MFMA32(wl[3072], xf, a43);
        }
        __builtin_amdgcn_s_setprio(0);

        // ---- cross-wave partial exchange: double-buffered xchg, ONE barrier
        char* xc = smem + 20480 + ((it & 1) << 12);
        if (wid == 1) {
            *(f32x4*)(xc +    0 + lane * 16) = a40;
            *(f32x4*)(xc + 1024 + lane * 16) = a41;
            *(f32x4*)(xc + 2048 + lane * 16) = a42;
            *(f32x4*)(xc + 3072 + lane * 16) = a43;
        }
        __syncthreads();   // wave1 proceeds into tile t+1 (other xchg buffer)

        if (wid == 0) {
            a40 += *(const f32x4*)(xc +    0 + lane * 16);
            a41 += *(const f32x4*)(xc + 1024 + lane * 16);
            a42 += *(const f32x4*)(xc + 2048 + lane * 16);
            a43 += *(const f32x4*)(xc + 3072 + lane * 16);

            // ---- Phase D: register pack+leaky of h1 (A-frags for E) ----
            f16x4 pd0 = lk_pk4(a40), pd1 = lk_pk4(a41);
            f16x4 pd2 = lk_pk4(a42), pd3 = lk_pk4(a43);

            // ---- Phase E: h2 = h1 @ Wl2 + bl2 (4-chain 16x16x16 per nt) --
            f32x4 a50 = {c0, c0, c0, c0};
            f32x4 a51 = {c1, c1, c1, c1};
            a50 = MFMA16(pd0, l200, a50);
            a51 = MFMA16(pd0, l201, a51);
            a50 = MFMA16(pd1, l210, a50);
            a51 = MFMA16(pd1, l211, a51);
            a50 = MFMA16(pd2, l220, a50);
            a51 = MFMA16(pd2, l221, a51);
            a50 = MFMA16(pd3, l230, a50);
            a51 = MFMA16(pd3, l231, a51);

            // ---- Phase F: out[b=4h+r] = sum_l2 leaky(h2) Wl3 + bl3 ----
            #pragma unroll
            for (int r = 0; r < 4; ++r) {
                float acc = leaky(a50[r]) * w30 + leaky(a51[r]) * w31;
                acc += __shfl_xor(acc, 1);
                acc += __shfl_xor(acc, 2);
                acc += __shfl_xor(acc, 4);
                acc += __shfl_xor(acc, 8);
                if (m15 == 0) out[b0 + h * 4 + r] = acc + bl3s;
            }
        }

        // ---- rotate prefetched rows ----
        if (more) { c00 = n00; c01 = n01; c10 = n10; c11 = n11; }
    }
}

extern "C" void kernel_launch(void* const* d_in, const int* in_sizes, int n_in,
                              void* d_out, int out_size, void* d_ws, size_t ws_size,
                              hipStream_t stream)
{
    const float* adj  = (const float*)d_in[0];
    const float* Wp1  = (const float*)d_in[1];
    const float* bp1  = (const float*)d_in[2];
    const float* Wp2  = (const float*)d_in[3];
    const float* bp2  = (const float*)d_in[4];
    const float* Wn1  = (const float*)d_in[5];
    const float* bn1  = (const float*)d_in[6];
    const float* Wn2  = (const float*)d_in[7];
    const float* bn2  = (const float*)d_in[8];
    const float* Wl1  = (const float*)d_in[9];
    const float* bl1  = (const float*)d_in[10];
    const float* Wl2  = (const float*)d_in[11];
    const float* bl2  = (const float*)d_in[12];
    const float* Wl3  = (const float*)d_in[13];
    const float* bl3  = (const float*)d_in[14];
    f16* ws = (f16*)d_ws;
    float* out = (float*)d_out;

    // 84*512 + 24*256 = 49152 f16; 192 blocks x 256 threads
    hipLaunchKernelGGL(disc_prepack, dim3(192), dim3(256), 0, stream,
                       Wp1, Wp2, Wn1, Wn2, Wl1, Wl2, ws);

    const int ldsBytes = 28672;  // 2 x 10240 wave areas + 2 x 4096 xchg
    hipFuncSetAttribute(reinterpret_cast<const void*>(disc_main),
                        hipFuncAttributeMaxDynamicSharedMemorySize, ldsBytes);
    hipLaunchKernelGGL(disc_main, dim3(8192 / TILES), dim3(128), ldsBytes, stream,
                       adj, bp1, bp2, bn1, bn2, bl1, bl2, bl3, Wl3, ws, out);
}